// Round 2
// baseline (187.702 us; speedup 1.0000x reference)
//
#include <hip/hip_runtime.h>

// Problem constants
#define NSEQ 64
#define LL   256
#define DD   256
#define HH   8
#define HDIM 32

typedef short short8  __attribute__((ext_vector_type(8)));
typedef short short4v __attribute__((ext_vector_type(4)));
typedef float float4v __attribute__((ext_vector_type(4)));

#define MFMA16(a,b,c) __builtin_amdgcn_mfma_f32_16x16x32_bf16((a),(b),(c),0,0,0)

__device__ __forceinline__ float4v zero4() {
  float4v z;
  z[0] = 0.f; z[1] = 0.f; z[2] = 0.f; z[3] = 0.f;
  return z;
}

__device__ __forceinline__ short f2b(float f) {
  unsigned u = __float_as_uint(f);
  u = (u + 0x7fffu + ((u >> 16) & 1u)) >> 16;   // RNE
  return (short)u;
}

__device__ __forceinline__ float b2f(short s) {
  return __uint_as_float(((unsigned)(unsigned short)s) << 16);
}

__device__ __forceinline__ short8 cvt8(const float* p) {
  float4 a = *(const float4*)p;
  float4 b = *(const float4*)(p + 4);
  short8 r;
  r[0] = f2b(a.x); r[1] = f2b(a.y); r[2] = f2b(a.z); r[3] = f2b(a.w);
  r[4] = f2b(b.x); r[5] = f2b(b.y); r[6] = f2b(b.z); r[7] = f2b(b.w);
  return r;
}

// async global->LDS, 16B per lane. LDS dest must be wave-uniform-base + lane*16.
__device__ __forceinline__ void ld_lds16(const void* g, void* l) {
  __builtin_amdgcn_global_load_lds(
      (const __attribute__((address_space(1))) unsigned int*)g,
      (__attribute__((address_space(3))) unsigned int*)l, 16, 0, 0);
}
#define WAIT_VM0() __builtin_amdgcn_s_waitcnt(0x0F70)   // vmcnt(0) only

// ---- workspace layout (bytes); total ~34.5 MB (MSA16 and O share) ----
#define WT_OFF    0                            // 4 x 256x256 bf16 (Wq^T,Wk^T,Wv^T,Wo^T) [ch][k]
#define PB_OFF    (4*65536*2)                  // pb bf16 [h][i][j] (1MB) + fragments (1MB)
#define PBF_OFF   (PB_OFF + 8*65536*2)         // pb bf16 fragments [h][it][jt][lane][4]
#define Q_OFF     (PB_OFF + 8*65536*4)         // per-head q_h[n][h][i][hd] bf16
#define K_OFF     (Q_OFF  + 16384*256*2)       // per-head k_h[n][h][j][hd] bf16
#define VT_OFF    (K_OFF  + 16384*256*2)       // [n][h][hd][j] bf16
#define MSA16_OFF (VT_OFF + 16384*256*2)       // 16384x256 bf16 (dead after k2)
#define O_OFF     MSA16_OFF                    // k3 output overlays MSA16

// ============================================================================
// K1: pb GEMM (256) + weight transpose (1024) + msa->bf16 (512) = 1792 blocks
// ============================================================================
__global__ __launch_bounds__(256) void k1_prep(
    const float* __restrict__ msa,  const float* __restrict__ pair,
    const float* __restrict__ Wq,   const float* __restrict__ Wk,
    const float* __restrict__ Wv,   const float* __restrict__ Wpb,
    const float* __restrict__ bpb,  const float* __restrict__ Wo,
    char* __restrict__ ws)
{
  __shared__ short ldsWt[16 * 136];   // Wpb^T bf16, rows 8..15 zero, ld=136 (pad)
  int bx = blockIdx.x, tid = threadIdx.x;
  if (bx < 256) {
    short* pb16 = (short*)(ws + PB_OFF);
    for (int i = tid; i < 16 * 136; i += 256) ldsWt[i] = 0;
    __syncthreads();
    {
      float4 wv4 = *(const float4*)&Wpb[tid * 4];
      int kk = (tid * 4) >> 3, n0 = (tid * 4) & 7;
      ldsWt[(n0 + 0) * 136 + kk] = f2b(wv4.x);
      ldsWt[(n0 + 1) * 136 + kk] = f2b(wv4.y);
      ldsWt[(n0 + 2) * 136 + kk] = f2b(wv4.z);
      ldsWt[(n0 + 3) * 136 + kk] = f2b(wv4.w);
    }
    __syncthreads();
    int w = tid >> 6, l = tid & 63, q = l >> 4, c = l & 15;
    int base = bx * 256 + w * 64;          // block bx covers pair row i=bx, all j
    float bias = bpb[c & 7];
    short8 bf[4];
#pragma unroll
    for (int ks = 0; ks < 4; ks++)
      bf[ks] = *(const short8*)&ldsWt[c * 136 + ks * 32 + q * 8];
    float4v acc[4];
#pragma unroll
    for (int mt = 0; mt < 4; mt++) acc[mt] = zero4();
#pragma unroll
    for (int ks = 0; ks < 4; ks++) {
#pragma unroll
      for (int mt = 0; mt < 4; mt++) {
        short8 af = cvt8(&pair[(base + mt * 16 + c) * 128 + ks * 32 + q * 8]);
        acc[mt] = MFMA16(af, bf[ks], acc[mt]);
      }
    }
    if (c < 8) {
#pragma unroll
      for (int mt = 0; mt < 4; mt++) {
        short4v o;
#pragma unroll
        for (int r = 0; r < 4; r++) o[r] = f2b(acc[mt][r] + bias);
        *(short4v*)&pb16[c * 65536 + base + mt * 16 + q * 4] = o;
      }
    }
  } else if (bx < 1280) {
    // weight transpose: wt[n][k] = W[k][n], bf16
    int b2 = bx - 256;
    int mat = b2 >> 8, r = b2 & 255;
    const float* W = (mat == 0) ? Wq : (mat == 1) ? Wk : (mat == 2) ? Wv : Wo;
    short* wt = (short*)(ws + WT_OFF) + mat * 65536;
    wt[tid * 256 + r] = f2b(W[r * 256 + tid]);
  } else {
    // msa -> bf16 row-major
    int b3 = bx - 1280;                 // 0..511, 32 rows each
    const float* src = msa + b3 * 8192;
    short* dst = (short*)(ws + MSA16_OFF) + b3 * 8192;
#pragma unroll
    for (int i = 0; i < 8; i++) {
      int idx = i * 1024 + tid * 4;
      float4 v = *(const float4*)&src[idx];
      short4v s;
      s[0] = f2b(v.x); s[1] = f2b(v.y); s[2] = f2b(v.z); s[3] = f2b(v.w);
      *(short4v*)&dst[idx] = s;
    }
  }
}

// ============================================================================
// K2: QKV GEMM (768 blocks) + pb fragment repack (128 blocks) = 896 blocks.
// GEMM: C[16384x768] = msa16 @ [Wq^T;Wk^T;Wv^T], 128x128 tiles, BK=128,
// LDS-staged via global_load_lds + XOR swizzle. Q/K written per-head packed.
// ============================================================================
__global__ __launch_bounds__(256) void k2_qkv(
    const float* __restrict__ bq, const float* __restrict__ bk,
    const float* __restrict__ bv, char* __restrict__ ws)
{
  __shared__ __align__(16) short lsA[128 * 128];
  __shared__ __align__(16) short lsB[128 * 128];
  int bx = blockIdx.x, tid = threadIdx.x;
  if (bx >= 768) {
    // pb repack: pb16[h][i][j] -> fragments pbf[h][it][jt][lane][reg] (bf16)
    int b = bx - 768;                   // 0..127
    int it16 = b & 15;
    const short* src = (const short*)(ws + PB_OFF) + (b >> 4) * 65536 + it16 * 4096;
    short* pbf = (short*)(ws + PBF_OFF);
    short* lt = lsA;                    // 16 x 264
#pragma unroll
    for (int i2 = 0; i2 < 2; i2++) {
      int idx = i2 * 2048 + tid * 8;
      *(short8*)&lt[(idx >> 8) * 264 + (idx & 255)] = *(const short8*)&src[idx];
    }
    __syncthreads();
#pragma unroll
    for (int i2 = 0; i2 < 4; i2++) {
      int fid = i2 * 256 + tid;
      int jt = fid >> 6, lane = fid & 63;
      int qp = lane >> 4, cp = lane & 15;
      short4v v;
#pragma unroll
      for (int r = 0; r < 4; r++)
        v[r] = lt[(qp * 4 + r) * 264 + jt * 16 + cp];
      *(short4v*)&pbf[((b * 16 + jt) * 64 + lane) * 4] = v;
    }
    return;
  }
  int rt = bx & 127, ct = bx >> 7;       // row-tile, col-tile
  int m = ct >> 1, cb = (ct & 1) * 128;  // matrix, ch base within matrix
  int R0 = rt * 128;
  const short* msa16 = (const short*)(ws + MSA16_OFF);
  const short* wt = (const short*)(ws + WT_OFF) + m * 65536;
  int w = tid >> 6, l = tid & 63, q = l >> 4, c = l & 15;
  int WR = (w & 1) * 64, WC = (w >> 1) * 64;
  float4v acc[4][4];
#pragma unroll
  for (int mt = 0; mt < 4; mt++)
#pragma unroll
    for (int nt = 0; nt < 4; nt++) acc[mt][nt] = zero4();

#pragma unroll 1
  for (int kk = 0; kk < 2; kk++) {
    if (kk) __syncthreads();
#pragma unroll
    for (int i = 0; i < 8; i++) {
      int ci = i * 256 + tid;
      int r = ci >> 4, pos = ci & 15;
      int kc = pos ^ (r & 7);
      ld_lds16(&msa16[(R0 + r) * 256 + kk * 128 + kc * 8], &lsA[ci * 8]);
    }
#pragma unroll
    for (int i = 0; i < 8; i++) {
      int ci = i * 256 + tid;
      int r = ci >> 4, pos = ci & 15;
      int kc = pos ^ (r & 7);
      ld_lds16(&wt[(cb + r) * 256 + kk * 128 + kc * 8], &lsB[ci * 8]);
    }
    WAIT_VM0();
    __syncthreads();
#pragma unroll
    for (int ks = 0; ks < 4; ks++) {
      short8 af[4], bf[4];
#pragma unroll
      for (int mt = 0; mt < 4; mt++) {
        int r = WR + mt * 16 + c;
        int phys = (ks * 4 + q) ^ (r & 7);
        af[mt] = *(const short8*)&lsA[r * 128 + phys * 8];
      }
#pragma unroll
      for (int nt = 0; nt < 4; nt++) {
        int r = WC + nt * 16 + c;
        int phys = (ks * 4 + q) ^ (r & 7);
        bf[nt] = *(const short8*)&lsB[r * 128 + phys * 8];
      }
#pragma unroll
      for (int mt = 0; mt < 4; mt++)
#pragma unroll
        for (int nt = 0; nt < 4; nt++)
          acc[mt][nt] = MFMA16(af[mt], bf[nt], acc[mt][nt]);
    }
  }

  const float* bp = (m == 0) ? bq : (m == 1) ? bk : bv;
  int n = R0 >> 8;
  if (m < 2) {
    // per-head packed: dst[n][h][i][hd]
    short* dst = (short*)(ws + (m == 0 ? Q_OFF : K_OFF));
#pragma unroll
    for (int nt = 0; nt < 4; nt++) {
      int ch = cb + WC + nt * 16 + c;
      float bb = bp[ch];
      int h = ch >> 5, hd = ch & 31;
#pragma unroll
      for (int mt = 0; mt < 4; mt++) {
        int i0 = (R0 & 255) + WR + mt * 16 + q * 4;
#pragma unroll
        for (int r = 0; r < 4; r++)
          dst[((n * HH + h) * 256 + i0 + r) * HDIM + hd] = f2b(acc[mt][nt][r] + bb);
      }
    }
  } else {
    short* vt = (short*)(ws + VT_OFF);
#pragma unroll
    for (int nt = 0; nt < 4; nt++) {
      int ch = cb + WC + nt * 16 + c;
      float bb = bp[ch];
#pragma unroll
      for (int mt = 0; mt < 4; mt++) {
        int j0 = (R0 & 255) + WR + mt * 16 + q * 4;
        short4v s4;
#pragma unroll
        for (int r = 0; r < 4; r++) s4[r] = f2b(acc[mt][nt][r] + bb);
        *(short4v*)&vt[((n * HH + (ch >> 5)) * HDIM + (ch & 31)) * 256 + j0] = s4;
      }
    }
  }
}

// ============================================================================
// K3: attention. 2048 blocks: bx = qq*512 + (n*8+h) so qq-siblings share XCD.
// ============================================================================
__global__ __launch_bounds__(256) void k3_attn(char* __restrict__ ws)
{
  __shared__ short P[64 * 264];          // 4 waves x 16 rows, ld=264 pad
  int bx = blockIdx.x, tid = threadIdx.x;
  int qq = bx >> 9, grp = bx & 511;
  int n = grp >> 3, h = grp & 7;
  int w = tid >> 6, l = tid & 63, q = l >> 4, c = l & 15;
  const short* qh = (const short*)(ws + Q_OFF) + (n * HH + h) * 256 * HDIM;
  const short* kh = (const short*)(ws + K_OFF) + (n * HH + h) * 256 * HDIM;
  const short* vt = (const short*)(ws + VT_OFF) + (n * HH + h) * HDIM * 256;
  const short* pbf = (const short*)(ws + PBF_OFF) + (h * 16 + qq * 4 + w) * 16 * 256;
  short* os = (short*)(ws + O_OFF);
  const float scale = 0.17677669529663687f;   // 1/sqrt(32)
  int i0 = qq * 64 + w * 16;             // this wave's 16 query rows
  short8 aq = *(const short8*)&qh[(i0 + c) * HDIM + q * 8];
  float4v s[16];
#pragma unroll
  for (int jt = 0; jt < 16; jt++) {
    short8 bk8 = *(const short8*)&kh[(jt * 16 + c) * HDIM + q * 8];
    s[jt] = MFMA16(aq, bk8, zero4());
  }
  // scale + pair bias from pre-packed fragments (b64 per jt)
#pragma unroll
  for (int jt = 0; jt < 16; jt++) {
    short4v pv = *(const short4v*)&pbf[(jt * 64 + l) * 4];
#pragma unroll
    for (int r = 0; r < 4; r++)
      s[jt][r] = __builtin_fmaf(s[jt][r], scale, b2f(pv[r]));
  }
  float inv[4];
#pragma unroll
  for (int r = 0; r < 4; r++) {
    float m = s[0][r];
#pragma unroll
    for (int jt = 1; jt < 16; jt++) m = fmaxf(m, s[jt][r]);
    m = fmaxf(m, __shfl_xor(m, 1, 64));
    m = fmaxf(m, __shfl_xor(m, 2, 64));
    m = fmaxf(m, __shfl_xor(m, 4, 64));
    m = fmaxf(m, __shfl_xor(m, 8, 64));
    float rs = 0.f;
#pragma unroll
    for (int jt = 0; jt < 16; jt++) {
      float p = __expf(s[jt][r] - m);
      s[jt][r] = p;
      rs += p;
    }
    rs += __shfl_xor(rs, 1, 64);
    rs += __shfl_xor(rs, 2, 64);
    rs += __shfl_xor(rs, 4, 64);
    rs += __shfl_xor(rs, 8, 64);
    inv[r] = 1.f / rs;
  }
#pragma unroll
  for (int jt = 0; jt < 16; jt++)
#pragma unroll
    for (int r = 0; r < 4; r++)
      P[(w * 16 + q * 4 + r) * 264 + jt * 16 + c] = f2b(s[jt][r]);
  float4v o0 = zero4(), o1 = zero4();
#pragma unroll
  for (int kk = 0; kk < 8; kk++) {
    short8 ap = *(const short8*)&P[(w * 16 + c) * 264 + kk * 32 + q * 8];
    short8 b0 = *(const short8*)&vt[c * 256 + kk * 32 + q * 8];
    short8 b1 = *(const short8*)&vt[(16 + c) * 256 + kk * 32 + q * 8];
    o0 = MFMA16(ap, b0, o0);
    o1 = MFMA16(ap, b1, o1);
  }
#pragma unroll
  for (int r = 0; r < 4; r++) {
    os[(n * 256 + i0 + q * 4 + r) * 256 + h * 32 + c]      = f2b(o0[r] * inv[r]);
    os[(n * 256 + i0 + q * 4 + r) * 256 + h * 32 + 16 + c] = f2b(o1[r] * inv[r]);
  }
}

// ============================================================================
// K4: out-proj + bias + residual + LayerNorm. NO LDS staging: A (attn out)
// and B (Wo^T) fragments read directly from global (both L2-resident bf16).
// 512 blocks x 4 waves; block = 32 rows x 256 cols; wave = 16 rows x 128 cols
// (rg = row-group, ch2 = col-half). LN stats cross the 2 col-half waves via a
// 512B LDS reduce -- the only barrier in the kernel.
// ============================================================================
__global__ __launch_bounds__(256) void k4_out(
    const float* __restrict__ msa, const float* __restrict__ bo,
    const float* __restrict__ gamma, const float* __restrict__ beta,
    const char* __restrict__ ws, float* __restrict__ out)
{
  __shared__ float sred[2][32][2];       // [s1|s2][row-in-block][col-half]
  int bx = blockIdx.x, tid = threadIdx.x;
  int w = tid >> 6, l = tid & 63, q = l >> 4, c = l & 15;
  int rg = w >> 1, ch2 = w & 1;          // row-group (0/1), col-half (0/1)
  int R0 = bx * 32 + rg * 16;            // this wave's 16 output rows
  int C0 = ch2 * 128;                    // this wave's 128 output cols
  const short* osrc = (const short*)(ws + O_OFF);
  const short* wto  = (const short*)(ws + WT_OFF) + 3 * 65536;

  float4v acc[8];
#pragma unroll
  for (int nt = 0; nt < 8; nt++) acc[nt] = zero4();

#pragma unroll
  for (int ks = 0; ks < 8; ks++) {
    short8 af = *(const short8*)&osrc[(R0 + c) * 256 + ks * 32 + q * 8];
#pragma unroll
    for (int nt = 0; nt < 8; nt++) {
      short8 bf = *(const short8*)&wto[(C0 + nt * 16 + c) * 256 + ks * 32 + q * 8];
      acc[nt] = MFMA16(af, bf, acc[nt]);
    }
  }

  // bias + residual + stats over this wave's 128 cols
  float s1[4] = {0, 0, 0, 0}, s2[4] = {0, 0, 0, 0};
#pragma unroll
  for (int nt = 0; nt < 8; nt++) {
    float bb = bo[C0 + nt * 16 + c];
#pragma unroll
    for (int r = 0; r < 4; r++) {
      float x = acc[nt][r] + bb + msa[(R0 + q * 4 + r) * 256 + C0 + nt * 16 + c];
      acc[nt][r] = x;
      s1[r] += x;
      s2[r] = __builtin_fmaf(x, x, s2[r]);
    }
  }
  // reduce over the 16 c-lanes (stays within each q-group)
#pragma unroll
  for (int r = 0; r < 4; r++) {
    s1[r] += __shfl_xor(s1[r], 1, 64); s2[r] += __shfl_xor(s2[r], 1, 64);
    s1[r] += __shfl_xor(s1[r], 2, 64); s2[r] += __shfl_xor(s2[r], 2, 64);
    s1[r] += __shfl_xor(s1[r], 4, 64); s2[r] += __shfl_xor(s2[r], 4, 64);
    s1[r] += __shfl_xor(s1[r], 8, 64); s2[r] += __shfl_xor(s2[r], 8, 64);
  }
  if (c == 0) {
#pragma unroll
    for (int r = 0; r < 4; r++) {
      sred[0][rg * 16 + q * 4 + r][ch2] = s1[r];
      sred[1][rg * 16 + q * 4 + r][ch2] = s2[r];
    }
  }
  __syncthreads();
  float mu[4], rsd[4];
#pragma unroll
  for (int r = 0; r < 4; r++) {
    int row = rg * 16 + q * 4 + r;
    float a = sred[0][row][0] + sred[0][row][1];
    float b = sred[1][row][0] + sred[1][row][1];
    float m = a * (1.f / 256.f);
    float v = __builtin_fmaf(-m, m, b * (1.f / 256.f));
    mu[r] = m;
    rsd[r] = rsqrtf(v + 1e-5f);
  }
#pragma unroll
  for (int nt = 0; nt < 8; nt++) {
    float g = gamma[C0 + nt * 16 + c], bt = beta[C0 + nt * 16 + c];
#pragma unroll
    for (int r = 0; r < 4; r++)
      out[(R0 + q * 4 + r) * 256 + C0 + nt * 16 + c] =
          (acc[nt][r] - mu[r]) * rsd[r] * g + bt;
  }
}

extern "C" void kernel_launch(void* const* d_in, const int* in_sizes, int n_in,
                              void* d_out, int out_size, void* d_ws, size_t ws_size,
                              hipStream_t stream)
{
  const float* msa   = (const float*)d_in[0];
  const float* pair  = (const float*)d_in[1];
  const float* Wq    = (const float*)d_in[2];
  const float* bq    = (const float*)d_in[3];
  const float* Wk    = (const float*)d_in[4];
  const float* bk    = (const float*)d_in[5];
  const float* Wv    = (const float*)d_in[6];
  const float* bv    = (const float*)d_in[7];
  const float* Wpb   = (const float*)d_in[8];
  const float* bpb   = (const float*)d_in[9];
  const float* Wo    = (const float*)d_in[10];
  const float* bo    = (const float*)d_in[11];
  const float* gamma = (const float*)d_in[12];
  const float* beta  = (const float*)d_in[13];
  char* ws = (char*)d_ws;
  float* out = (float*)d_out;

  hipLaunchKernelGGL(k1_prep, dim3(1792), dim3(256), 0, stream,
                     msa, pair, Wq, Wk, Wv, Wpb, bpb, Wo, ws);
  hipLaunchKernelGGL(k2_qkv, dim3(896), dim3(256), 0, stream,
                     bq, bk, bv, ws);
  hipLaunchKernelGGL(k3_attn, dim3(2048), dim3(256), 0, stream, ws);
  hipLaunchKernelGGL(k4_out, dim3(512), dim3(256), 0, stream,
                     msa, bo, gamma, beta, ws, out);
}

// Round 3
// 177.312 us; speedup vs baseline: 1.0586x; 1.0586x over previous
//
#include <hip/hip_runtime.h>

// Problem constants
#define NSEQ 64
#define LL   256
#define DD   256
#define HH   8
#define HDIM 32

typedef short short8  __attribute__((ext_vector_type(8)));
typedef short short4v __attribute__((ext_vector_type(4)));
typedef float float4v __attribute__((ext_vector_type(4)));

#define MFMA16(a,b,c) __builtin_amdgcn_mfma_f32_16x16x32_bf16((a),(b),(c),0,0,0)

__device__ __forceinline__ float4v zero4() {
  float4v z;
  z[0] = 0.f; z[1] = 0.f; z[2] = 0.f; z[3] = 0.f;
  return z;
}

__device__ __forceinline__ short f2b(float f) {
  unsigned u = __float_as_uint(f);
  u = (u + 0x7fffu + ((u >> 16) & 1u)) >> 16;   // RNE
  return (short)u;
}

__device__ __forceinline__ float b2f(short s) {
  return __uint_as_float(((unsigned)(unsigned short)s) << 16);
}

__device__ __forceinline__ short8 cvt8(const float* p) {
  float4 a = *(const float4*)p;
  float4 b = *(const float4*)(p + 4);
  short8 r;
  r[0] = f2b(a.x); r[1] = f2b(a.y); r[2] = f2b(a.z); r[3] = f2b(a.w);
  r[4] = f2b(b.x); r[5] = f2b(b.y); r[6] = f2b(b.z); r[7] = f2b(b.w);
  return r;
}

// async global->LDS, 16B per lane. LDS dest must be wave-uniform-base + lane*16.
__device__ __forceinline__ void ld_lds16(const void* g, void* l) {
  __builtin_amdgcn_global_load_lds(
      (const __attribute__((address_space(1))) unsigned int*)g,
      (__attribute__((address_space(3))) unsigned int*)l, 16, 0, 0);
}
#define WAIT_VM0() __builtin_amdgcn_s_waitcnt(0x0F70)   // vmcnt(0) only

// ---- workspace layout (bytes); total ~34.5 MB (MSA16 and O share) ----
#define WT_OFF    0                            // 4 x 256x256 bf16 (Wq^T,Wk^T,Wv^T,Wo^T) [ch][k]
#define PB_OFF    (4*65536*2)                  // pb bf16 [h][i][j] (1MB) + fragments (1MB)
#define PBF_OFF   (PB_OFF + 8*65536*2)         // pb bf16 fragments [h][it][jt][lane][4]
#define Q_OFF     (PB_OFF + 8*65536*4)         // per-head q_h[n][h][i][hd] bf16
#define K_OFF     (Q_OFF  + 16384*256*2)       // per-head k_h[n][h][j][hd] bf16
#define VT_OFF    (K_OFF  + 16384*256*2)       // [n][h][hd][j] bf16
#define MSA16_OFF (VT_OFF + 16384*256*2)       // 16384x256 bf16 (dead after k2)
#define O_OFF     MSA16_OFF                    // k3 output overlays MSA16

// ============================================================================
// K1: pb GEMM (256) + weight transpose (1024) + msa->bf16 (512) = 1792 blocks
// ============================================================================
__global__ __launch_bounds__(256) void k1_prep(
    const float* __restrict__ msa,  const float* __restrict__ pair,
    const float* __restrict__ Wq,   const float* __restrict__ Wk,
    const float* __restrict__ Wv,   const float* __restrict__ Wpb,
    const float* __restrict__ bpb,  const float* __restrict__ Wo,
    char* __restrict__ ws)
{
  __shared__ short ldsWt[16 * 136];   // Wpb^T bf16, rows 8..15 zero, ld=136 (pad)
  int bx = blockIdx.x, tid = threadIdx.x;
  if (bx < 256) {
    short* pb16 = (short*)(ws + PB_OFF);
    for (int i = tid; i < 16 * 136; i += 256) ldsWt[i] = 0;
    __syncthreads();
    {
      float4 wv4 = *(const float4*)&Wpb[tid * 4];
      int kk = (tid * 4) >> 3, n0 = (tid * 4) & 7;
      ldsWt[(n0 + 0) * 136 + kk] = f2b(wv4.x);
      ldsWt[(n0 + 1) * 136 + kk] = f2b(wv4.y);
      ldsWt[(n0 + 2) * 136 + kk] = f2b(wv4.z);
      ldsWt[(n0 + 3) * 136 + kk] = f2b(wv4.w);
    }
    __syncthreads();
    int w = tid >> 6, l = tid & 63, q = l >> 4, c = l & 15;
    int base = bx * 256 + w * 64;          // block bx covers pair row i=bx, all j
    float bias = bpb[c & 7];
    short8 bf[4];
#pragma unroll
    for (int ks = 0; ks < 4; ks++)
      bf[ks] = *(const short8*)&ldsWt[c * 136 + ks * 32 + q * 8];
    float4v acc[4];
#pragma unroll
    for (int mt = 0; mt < 4; mt++) acc[mt] = zero4();
#pragma unroll
    for (int ks = 0; ks < 4; ks++) {
#pragma unroll
      for (int mt = 0; mt < 4; mt++) {
        short8 af = cvt8(&pair[(base + mt * 16 + c) * 128 + ks * 32 + q * 8]);
        acc[mt] = MFMA16(af, bf[ks], acc[mt]);
      }
    }
    if (c < 8) {
#pragma unroll
      for (int mt = 0; mt < 4; mt++) {
        short4v o;
#pragma unroll
        for (int r = 0; r < 4; r++) o[r] = f2b(acc[mt][r] + bias);
        *(short4v*)&pb16[c * 65536 + base + mt * 16 + q * 4] = o;
      }
    }
  } else if (bx < 1280) {
    // weight transpose: wt[n][k] = W[k][n], bf16
    int b2 = bx - 256;
    int mat = b2 >> 8, r = b2 & 255;
    const float* W = (mat == 0) ? Wq : (mat == 1) ? Wk : (mat == 2) ? Wv : Wo;
    short* wt = (short*)(ws + WT_OFF) + mat * 65536;
    wt[tid * 256 + r] = f2b(W[r * 256 + tid]);
  } else {
    // msa -> bf16 row-major
    int b3 = bx - 1280;                 // 0..511, 32 rows each
    const float* src = msa + b3 * 8192;
    short* dst = (short*)(ws + MSA16_OFF) + b3 * 8192;
#pragma unroll
    for (int i = 0; i < 8; i++) {
      int idx = i * 1024 + tid * 4;
      float4 v = *(const float4*)&src[idx];
      short4v s;
      s[0] = f2b(v.x); s[1] = f2b(v.y); s[2] = f2b(v.z); s[3] = f2b(v.w);
      *(short4v*)&dst[idx] = s;
    }
  }
}

// ============================================================================
// K2: QKV GEMM (768 blocks) + pb fragment repack (128 blocks) = 896 blocks.
// GEMM: C[16384x768] = msa16 @ [Wq^T;Wk^T;Wv^T], 128x128 tiles, BK=128,
// LDS-staged via global_load_lds + XOR swizzle. Q/K written per-head packed.
// ============================================================================
__global__ __launch_bounds__(256) void k2_qkv(
    const float* __restrict__ bq, const float* __restrict__ bk,
    const float* __restrict__ bv, char* __restrict__ ws)
{
  __shared__ __align__(16) short lsA[128 * 128];
  __shared__ __align__(16) short lsB[128 * 128];
  int bx = blockIdx.x, tid = threadIdx.x;
  if (bx >= 768) {
    // pb repack: pb16[h][i][j] -> fragments pbf[h][it][jt][lane][reg] (bf16)
    int b = bx - 768;                   // 0..127
    int it16 = b & 15;
    const short* src = (const short*)(ws + PB_OFF) + (b >> 4) * 65536 + it16 * 4096;
    short* pbf = (short*)(ws + PBF_OFF);
    short* lt = lsA;                    // 16 x 264
#pragma unroll
    for (int i2 = 0; i2 < 2; i2++) {
      int idx = i2 * 2048 + tid * 8;
      *(short8*)&lt[(idx >> 8) * 264 + (idx & 255)] = *(const short8*)&src[idx];
    }
    __syncthreads();
#pragma unroll
    for (int i2 = 0; i2 < 4; i2++) {
      int fid = i2 * 256 + tid;
      int jt = fid >> 6, lane = fid & 63;
      int qp = lane >> 4, cp = lane & 15;
      short4v v;
#pragma unroll
      for (int r = 0; r < 4; r++)
        v[r] = lt[(qp * 4 + r) * 264 + jt * 16 + cp];
      *(short4v*)&pbf[((b * 16 + jt) * 64 + lane) * 4] = v;
    }
    return;
  }
  int rt = bx & 127, ct = bx >> 7;       // row-tile, col-tile
  int m = ct >> 1, cb = (ct & 1) * 128;  // matrix, ch base within matrix
  int R0 = rt * 128;
  const short* msa16 = (const short*)(ws + MSA16_OFF);
  const short* wt = (const short*)(ws + WT_OFF) + m * 65536;
  int w = tid >> 6, l = tid & 63, q = l >> 4, c = l & 15;
  int WR = (w & 1) * 64, WC = (w >> 1) * 64;
  float4v acc[4][4];
#pragma unroll
  for (int mt = 0; mt < 4; mt++)
#pragma unroll
    for (int nt = 0; nt < 4; nt++) acc[mt][nt] = zero4();

#pragma unroll 1
  for (int kk = 0; kk < 2; kk++) {
    if (kk) __syncthreads();
#pragma unroll
    for (int i = 0; i < 8; i++) {
      int ci = i * 256 + tid;
      int r = ci >> 4, pos = ci & 15;
      int kc = pos ^ (r & 7);
      ld_lds16(&msa16[(R0 + r) * 256 + kk * 128 + kc * 8], &lsA[ci * 8]);
    }
#pragma unroll
    for (int i = 0; i < 8; i++) {
      int ci = i * 256 + tid;
      int r = ci >> 4, pos = ci & 15;
      int kc = pos ^ (r & 7);
      ld_lds16(&wt[(cb + r) * 256 + kk * 128 + kc * 8], &lsB[ci * 8]);
    }
    WAIT_VM0();
    __syncthreads();
#pragma unroll
    for (int ks = 0; ks < 4; ks++) {
      short8 af[4], bf[4];
#pragma unroll
      for (int mt = 0; mt < 4; mt++) {
        int r = WR + mt * 16 + c;
        int phys = (ks * 4 + q) ^ (r & 7);
        af[mt] = *(const short8*)&lsA[r * 128 + phys * 8];
      }
#pragma unroll
      for (int nt = 0; nt < 4; nt++) {
        int r = WC + nt * 16 + c;
        int phys = (ks * 4 + q) ^ (r & 7);
        bf[nt] = *(const short8*)&lsB[r * 128 + phys * 8];
      }
#pragma unroll
      for (int mt = 0; mt < 4; mt++)
#pragma unroll
        for (int nt = 0; nt < 4; nt++)
          acc[mt][nt] = MFMA16(af[mt], bf[nt], acc[mt][nt]);
    }
  }

  const float* bp = (m == 0) ? bq : (m == 1) ? bk : bv;
  int n = R0 >> 8;
  if (m < 2) {
    // per-head packed: dst[n][h][i][hd]
    short* dst = (short*)(ws + (m == 0 ? Q_OFF : K_OFF));
#pragma unroll
    for (int nt = 0; nt < 4; nt++) {
      int ch = cb + WC + nt * 16 + c;
      float bb = bp[ch];
      int h = ch >> 5, hd = ch & 31;
#pragma unroll
      for (int mt = 0; mt < 4; mt++) {
        int i0 = (R0 & 255) + WR + mt * 16 + q * 4;
#pragma unroll
        for (int r = 0; r < 4; r++)
          dst[((n * HH + h) * 256 + i0 + r) * HDIM + hd] = f2b(acc[mt][nt][r] + bb);
      }
    }
  } else {
    short* vt = (short*)(ws + VT_OFF);
#pragma unroll
    for (int nt = 0; nt < 4; nt++) {
      int ch = cb + WC + nt * 16 + c;
      float bb = bp[ch];
#pragma unroll
      for (int mt = 0; mt < 4; mt++) {
        int j0 = (R0 & 255) + WR + mt * 16 + q * 4;
        short4v s4;
#pragma unroll
        for (int r = 0; r < 4; r++) s4[r] = f2b(acc[mt][nt][r] + bb);
        *(short4v*)&vt[((n * HH + (ch >> 5)) * HDIM + (ch & 31)) * 256 + j0] = s4;
      }
    }
  }
}

// ============================================================================
// K3: attention. 2048 blocks: bx = qq*512 + (n*8+h) so qq-siblings share XCD.
// ============================================================================
__global__ __launch_bounds__(256) void k3_attn(char* __restrict__ ws)
{
  __shared__ short P[64 * 264];          // 4 waves x 16 rows, ld=264 pad
  int bx = blockIdx.x, tid = threadIdx.x;
  int qq = bx >> 9, grp = bx & 511;
  int n = grp >> 3, h = grp & 7;
  int w = tid >> 6, l = tid & 63, q = l >> 4, c = l & 15;
  const short* qh = (const short*)(ws + Q_OFF) + (n * HH + h) * 256 * HDIM;
  const short* kh = (const short*)(ws + K_OFF) + (n * HH + h) * 256 * HDIM;
  const short* vt = (const short*)(ws + VT_OFF) + (n * HH + h) * HDIM * 256;
  const short* pbf = (const short*)(ws + PBF_OFF) + (h * 16 + qq * 4 + w) * 16 * 256;
  short* os = (short*)(ws + O_OFF);
  const float scale = 0.17677669529663687f;   // 1/sqrt(32)
  int i0 = qq * 64 + w * 16;             // this wave's 16 query rows
  short8 aq = *(const short8*)&qh[(i0 + c) * HDIM + q * 8];
  float4v s[16];
#pragma unroll
  for (int jt = 0; jt < 16; jt++) {
    short8 bk8 = *(const short8*)&kh[(jt * 16 + c) * HDIM + q * 8];
    s[jt] = MFMA16(aq, bk8, zero4());
  }
  // scale + pair bias from pre-packed fragments (b64 per jt)
#pragma unroll
  for (int jt = 0; jt < 16; jt++) {
    short4v pv = *(const short4v*)&pbf[(jt * 64 + l) * 4];
#pragma unroll
    for (int r = 0; r < 4; r++)
      s[jt][r] = __builtin_fmaf(s[jt][r], scale, b2f(pv[r]));
  }
  float inv[4];
#pragma unroll
  for (int r = 0; r < 4; r++) {
    float m = s[0][r];
#pragma unroll
    for (int jt = 1; jt < 16; jt++) m = fmaxf(m, s[jt][r]);
    m = fmaxf(m, __shfl_xor(m, 1, 64));
    m = fmaxf(m, __shfl_xor(m, 2, 64));
    m = fmaxf(m, __shfl_xor(m, 4, 64));
    m = fmaxf(m, __shfl_xor(m, 8, 64));
    float rs = 0.f;
#pragma unroll
    for (int jt = 0; jt < 16; jt++) {
      float p = __expf(s[jt][r] - m);
      s[jt][r] = p;
      rs += p;
    }
    rs += __shfl_xor(rs, 1, 64);
    rs += __shfl_xor(rs, 2, 64);
    rs += __shfl_xor(rs, 4, 64);
    rs += __shfl_xor(rs, 8, 64);
    inv[r] = 1.f / rs;
  }
#pragma unroll
  for (int jt = 0; jt < 16; jt++)
#pragma unroll
    for (int r = 0; r < 4; r++)
      P[(w * 16 + q * 4 + r) * 264 + jt * 16 + c] = f2b(s[jt][r]);
  float4v o0 = zero4(), o1 = zero4();
#pragma unroll
  for (int kk = 0; kk < 8; kk++) {
    short8 ap = *(const short8*)&P[(w * 16 + c) * 264 + kk * 32 + q * 8];
    short8 b0 = *(const short8*)&vt[c * 256 + kk * 32 + q * 8];
    short8 b1 = *(const short8*)&vt[(16 + c) * 256 + kk * 32 + q * 8];
    o0 = MFMA16(ap, b0, o0);
    o1 = MFMA16(ap, b1, o1);
  }
#pragma unroll
  for (int r = 0; r < 4; r++) {
    os[(n * 256 + i0 + q * 4 + r) * 256 + h * 32 + c]      = f2b(o0[r] * inv[r]);
    os[(n * 256 + i0 + q * 4 + r) * 256 + h * 32 + 16 + c] = f2b(o1[r] * inv[r]);
  }
}

// ============================================================================
// K4: out-proj + bias + residual + LayerNorm. LDS-staged (k2's proven swizzle
// pattern) but 32 rows/block: grid 512, LDS = 8KB A + 64KB B + 0.5KB reduce
// = 72.5KB -> 2 blocks/CU (vs round-0's 1 block/CU at grid 256). Wave layout:
// 2 row-groups x 2 col-halves; LN stats cross col-half waves via sred.
// ============================================================================
__global__ __launch_bounds__(256) void k4_out(
    const float* __restrict__ msa, const float* __restrict__ bo,
    const float* __restrict__ gamma, const float* __restrict__ beta,
    const char* __restrict__ ws, float* __restrict__ out)
{
  __shared__ __align__(16) short lsA[32 * 128];
  __shared__ __align__(16) short lsB[256 * 128];
  __shared__ float sred[2][32][2];       // [s1|s2][row-in-block][col-half]
  int bx = blockIdx.x, tid = threadIdx.x;
  int w = tid >> 6, l = tid & 63, q = l >> 4, c = l & 15;
  int rg = w >> 1, ch2 = w & 1;          // row-group (0/1), col-half (0/1)
  int R0 = bx * 32;                      // block's 32 rows
  int Rw = R0 + rg * 16;                 // this wave's 16 rows
  int C0 = ch2 * 128;                    // this wave's 128 cols
  const short* osrc = (const short*)(ws + O_OFF);
  const short* wto  = (const short*)(ws + WT_OFF) + 3 * 65536;

  float4v acc[8];
#pragma unroll
  for (int nt = 0; nt < 8; nt++) acc[nt] = zero4();

#pragma unroll 1
  for (int kk = 0; kk < 2; kk++) {
    if (kk) __syncthreads();
#pragma unroll
    for (int i = 0; i < 2; i++) {        // A: 32 rows x 128 k
      int ci = i * 256 + tid;
      int r = ci >> 4, pos = ci & 15;
      int kc = pos ^ (r & 7);
      ld_lds16(&osrc[(R0 + r) * 256 + kk * 128 + kc * 8], &lsA[ci * 8]);
    }
#pragma unroll
    for (int i = 0; i < 16; i++) {       // B: 256 ch x 128 k
      int ci = i * 256 + tid;
      int r = ci >> 4, pos = ci & 15;
      int kc = pos ^ (r & 7);
      ld_lds16(&wto[r * 256 + kk * 128 + kc * 8], &lsB[ci * 8]);
    }
    WAIT_VM0();
    __syncthreads();
#pragma unroll
    for (int ks = 0; ks < 4; ks++) {
      int rA = rg * 16 + c;
      int physA = (ks * 4 + q) ^ (rA & 7);
      short8 af = *(const short8*)&lsA[rA * 128 + physA * 8];
#pragma unroll
      for (int nt = 0; nt < 8; nt++) {
        int rB = C0 + nt * 16 + c;
        int phys = (ks * 4 + q) ^ (rB & 7);
        short8 bf = *(const short8*)&lsB[rB * 128 + phys * 8];
        acc[nt] = MFMA16(af, bf, acc[nt]);
      }
    }
  }

  // bias + residual + stats over this wave's 128 cols
  float s1[4] = {0, 0, 0, 0}, s2[4] = {0, 0, 0, 0};
#pragma unroll
  for (int nt = 0; nt < 8; nt++) {
    float bb = bo[C0 + nt * 16 + c];
#pragma unroll
    for (int r = 0; r < 4; r++) {
      float x = acc[nt][r] + bb + msa[(Rw + q * 4 + r) * 256 + C0 + nt * 16 + c];
      acc[nt][r] = x;
      s1[r] += x;
      s2[r] = __builtin_fmaf(x, x, s2[r]);
    }
  }
  // reduce over the 16 c-lanes (stays within each q-group)
#pragma unroll
  for (int r = 0; r < 4; r++) {
    s1[r] += __shfl_xor(s1[r], 1, 64); s2[r] += __shfl_xor(s2[r], 1, 64);
    s1[r] += __shfl_xor(s1[r], 2, 64); s2[r] += __shfl_xor(s2[r], 2, 64);
    s1[r] += __shfl_xor(s1[r], 4, 64); s2[r] += __shfl_xor(s2[r], 4, 64);
    s1[r] += __shfl_xor(s1[r], 8, 64); s2[r] += __shfl_xor(s2[r], 8, 64);
  }
  if (c == 0) {
#pragma unroll
    for (int r = 0; r < 4; r++) {
      sred[0][rg * 16 + q * 4 + r][ch2] = s1[r];
      sred[1][rg * 16 + q * 4 + r][ch2] = s2[r];
    }
  }
  __syncthreads();
  float mu[4], rsd[4];
#pragma unroll
  for (int r = 0; r < 4; r++) {
    int row = rg * 16 + q * 4 + r;
    float a = sred[0][row][0] + sred[0][row][1];
    float b = sred[1][row][0] + sred[1][row][1];
    float m = a * (1.f / 256.f);
    float v = __builtin_fmaf(-m, m, b * (1.f / 256.f));
    mu[r] = m;
    rsd[r] = rsqrtf(v + 1e-5f);
  }
#pragma unroll
  for (int nt = 0; nt < 8; nt++) {
    float g = gamma[C0 + nt * 16 + c], bt = beta[C0 + nt * 16 + c];
#pragma unroll
    for (int r = 0; r < 4; r++)
      out[(Rw + q * 4 + r) * 256 + C0 + nt * 16 + c] =
          (acc[nt][r] - mu[r]) * rsd[r] * g + bt;
  }
}

extern "C" void kernel_launch(void* const* d_in, const int* in_sizes, int n_in,
                              void* d_out, int out_size, void* d_ws, size_t ws_size,
                              hipStream_t stream)
{
  const float* msa   = (const float*)d_in[0];
  const float* pair  = (const float*)d_in[1];
  const float* Wq    = (const float*)d_in[2];
  const float* bq    = (const float*)d_in[3];
  const float* Wk    = (const float*)d_in[4];
  const float* bk    = (const float*)d_in[5];
  const float* Wv    = (const float*)d_in[6];
  const float* bv    = (const float*)d_in[7];
  const float* Wpb   = (const float*)d_in[8];
  const float* bpb   = (const float*)d_in[9];
  const float* Wo    = (const float*)d_in[10];
  const float* bo    = (const float*)d_in[11];
  const float* gamma = (const float*)d_in[12];
  const float* beta  = (const float*)d_in[13];
  char* ws = (char*)d_ws;
  float* out = (float*)d_out;

  hipLaunchKernelGGL(k1_prep, dim3(1792), dim3(256), 0, stream,
                     msa, pair, Wq, Wk, Wv, Wpb, bpb, Wo, ws);
  hipLaunchKernelGGL(k2_qkv, dim3(896), dim3(256), 0, stream,
                     bq, bk, bv, ws);
  hipLaunchKernelGGL(k3_attn, dim3(2048), dim3(256), 0, stream, ws);
  hipLaunchKernelGGL(k4_out, dim3(512), dim3(256), 0, stream,
                     msa, bo, gamma, beta, ws, out);
}

// Round 4
// 167.702 us; speedup vs baseline: 1.1193x; 1.0573x over previous
//
#include <hip/hip_runtime.h>

// Problem constants
#define NSEQ 64
#define LL   256
#define DD   256
#define HH   8
#define HDIM 32

typedef short short8  __attribute__((ext_vector_type(8)));
typedef short short4v __attribute__((ext_vector_type(4)));
typedef float float4v __attribute__((ext_vector_type(4)));

#define MFMA16(a,b,c) __builtin_amdgcn_mfma_f32_16x16x32_bf16((a),(b),(c),0,0,0)

__device__ __forceinline__ float4v zero4() {
  float4v z;
  z[0] = 0.f; z[1] = 0.f; z[2] = 0.f; z[3] = 0.f;
  return z;
}

__device__ __forceinline__ short f2b(float f) {
  unsigned u = __float_as_uint(f);
  u = (u + 0x7fffu + ((u >> 16) & 1u)) >> 16;   // RNE
  return (short)u;
}

__device__ __forceinline__ float b2f(short s) {
  return __uint_as_float(((unsigned)(unsigned short)s) << 16);
}

__device__ __forceinline__ short8 cvt8(const float* p) {
  float4 a = *(const float4*)p;
  float4 b = *(const float4*)(p + 4);
  short8 r;
  r[0] = f2b(a.x); r[1] = f2b(a.y); r[2] = f2b(a.z); r[3] = f2b(a.w);
  r[4] = f2b(b.x); r[5] = f2b(b.y); r[6] = f2b(b.z); r[7] = f2b(b.w);
  return r;
}

// async global->LDS, 16B per lane. LDS dest must be wave-uniform-base + lane*16.
__device__ __forceinline__ void ld_lds16(const void* g, void* l) {
  __builtin_amdgcn_global_load_lds(
      (const __attribute__((address_space(1))) unsigned int*)g,
      (__attribute__((address_space(3))) unsigned int*)l, 16, 0, 0);
}
#define WAIT_VM0() __builtin_amdgcn_s_waitcnt(0x0F70)   // vmcnt(0) only

// ---- workspace layout (bytes); total ~34.5 MB (MSA16 and O share) ----
#define WT_OFF    0                            // 4 x 256x256 bf16 (Wq^T,Wk^T,Wv^T,Wo^T) [ch][k]
#define PB_OFF    (4*65536*2)                  // pb bf16 [h][i][j] (1MB) + fragments (1MB)
#define PBF_OFF   (PB_OFF + 8*65536*2)         // pb bf16 fragments [h][it][jt][lane][4]
#define Q_OFF     (PB_OFF + 8*65536*4)         // per-head q_h[n][h][i][hd] bf16
#define K_OFF     (Q_OFF  + 16384*256*2)       // per-head k_h[n][h][j][hd] bf16
#define VT_OFF    (K_OFF  + 16384*256*2)       // [n][h][hd][j] bf16
#define MSA16_OFF (VT_OFF + 16384*256*2)       // 16384x256 bf16 (dead after k2)
#define O_OFF     MSA16_OFF                    // k3 output overlays MSA16

// ============================================================================
// K1: pb GEMM (256) + weight transpose (1024) + msa->bf16 (512) = 1792 blocks
// ============================================================================
__global__ __launch_bounds__(256) void k1_prep(
    const float* __restrict__ msa,  const float* __restrict__ pair,
    const float* __restrict__ Wq,   const float* __restrict__ Wk,
    const float* __restrict__ Wv,   const float* __restrict__ Wpb,
    const float* __restrict__ bpb,  const float* __restrict__ Wo,
    char* __restrict__ ws)
{
  __shared__ short ldsWt[16 * 136];   // Wpb^T bf16, rows 8..15 zero, ld=136 (pad)
  int bx = blockIdx.x, tid = threadIdx.x;
  if (bx < 256) {
    short* pb16 = (short*)(ws + PB_OFF);
    for (int i = tid; i < 16 * 136; i += 256) ldsWt[i] = 0;
    __syncthreads();
    {
      float4 wv4 = *(const float4*)&Wpb[tid * 4];
      int kk = (tid * 4) >> 3, n0 = (tid * 4) & 7;
      ldsWt[(n0 + 0) * 136 + kk] = f2b(wv4.x);
      ldsWt[(n0 + 1) * 136 + kk] = f2b(wv4.y);
      ldsWt[(n0 + 2) * 136 + kk] = f2b(wv4.z);
      ldsWt[(n0 + 3) * 136 + kk] = f2b(wv4.w);
    }
    __syncthreads();
    int w = tid >> 6, l = tid & 63, q = l >> 4, c = l & 15;
    int base = bx * 256 + w * 64;          // block bx covers pair row i=bx, all j
    float bias = bpb[c & 7];
    short8 bf[4];
#pragma unroll
    for (int ks = 0; ks < 4; ks++)
      bf[ks] = *(const short8*)&ldsWt[c * 136 + ks * 32 + q * 8];
    float4v acc[4];
#pragma unroll
    for (int mt = 0; mt < 4; mt++) acc[mt] = zero4();
#pragma unroll
    for (int ks = 0; ks < 4; ks++) {
#pragma unroll
      for (int mt = 0; mt < 4; mt++) {
        short8 af = cvt8(&pair[(base + mt * 16 + c) * 128 + ks * 32 + q * 8]);
        acc[mt] = MFMA16(af, bf[ks], acc[mt]);
      }
    }
    if (c < 8) {
#pragma unroll
      for (int mt = 0; mt < 4; mt++) {
        short4v o;
#pragma unroll
        for (int r = 0; r < 4; r++) o[r] = f2b(acc[mt][r] + bias);
        *(short4v*)&pb16[c * 65536 + base + mt * 16 + q * 4] = o;
      }
    }
  } else if (bx < 1280) {
    // weight transpose: wt[n][k] = W[k][n], bf16
    int b2 = bx - 256;
    int mat = b2 >> 8, r = b2 & 255;
    const float* W = (mat == 0) ? Wq : (mat == 1) ? Wk : (mat == 2) ? Wv : Wo;
    short* wt = (short*)(ws + WT_OFF) + mat * 65536;
    wt[tid * 256 + r] = f2b(W[r * 256 + tid]);
  } else {
    // msa -> bf16 row-major
    int b3 = bx - 1280;                 // 0..511, 32 rows each
    const float* src = msa + b3 * 8192;
    short* dst = (short*)(ws + MSA16_OFF) + b3 * 8192;
#pragma unroll
    for (int i = 0; i < 8; i++) {
      int idx = i * 1024 + tid * 4;
      float4 v = *(const float4*)&src[idx];
      short4v s;
      s[0] = f2b(v.x); s[1] = f2b(v.y); s[2] = f2b(v.z); s[3] = f2b(v.w);
      *(short4v*)&dst[idx] = s;
    }
  }
}

// ============================================================================
// K2: QKV GEMM (768 blocks) + pb fragment repack (128 blocks) = 896 blocks.
// GEMM: C[16384x768] = msa16 @ [Wq^T;Wk^T;Wv^T], 128x128 tiles, BK=128,
// LDS-staged via global_load_lds + XOR swizzle. Q/K written per-head packed.
// ============================================================================
__global__ __launch_bounds__(256) void k2_qkv(
    const float* __restrict__ bq, const float* __restrict__ bk,
    const float* __restrict__ bv, char* __restrict__ ws)
{
  __shared__ __align__(16) short lsA[128 * 128];
  __shared__ __align__(16) short lsB[128 * 128];
  int bx = blockIdx.x, tid = threadIdx.x;
  if (bx >= 768) {
    // pb repack: pb16[h][i][j] -> fragments pbf[h][it][jt][lane][reg] (bf16)
    int b = bx - 768;                   // 0..127
    int it16 = b & 15;
    const short* src = (const short*)(ws + PB_OFF) + (b >> 4) * 65536 + it16 * 4096;
    short* pbf = (short*)(ws + PBF_OFF);
    short* lt = lsA;                    // 16 x 264
#pragma unroll
    for (int i2 = 0; i2 < 2; i2++) {
      int idx = i2 * 2048 + tid * 8;
      *(short8*)&lt[(idx >> 8) * 264 + (idx & 255)] = *(const short8*)&src[idx];
    }
    __syncthreads();
#pragma unroll
    for (int i2 = 0; i2 < 4; i2++) {
      int fid = i2 * 256 + tid;
      int jt = fid >> 6, lane = fid & 63;
      int qp = lane >> 4, cp = lane & 15;
      short4v v;
#pragma unroll
      for (int r = 0; r < 4; r++)
        v[r] = lt[(qp * 4 + r) * 264 + jt * 16 + cp];
      *(short4v*)&pbf[((b * 16 + jt) * 64 + lane) * 4] = v;
    }
    return;
  }
  int rt = bx & 127, ct = bx >> 7;       // row-tile, col-tile
  int m = ct >> 1, cb = (ct & 1) * 128;  // matrix, ch base within matrix
  int R0 = rt * 128;
  const short* msa16 = (const short*)(ws + MSA16_OFF);
  const short* wt = (const short*)(ws + WT_OFF) + m * 65536;
  int w = tid >> 6, l = tid & 63, q = l >> 4, c = l & 15;
  int WR = (w & 1) * 64, WC = (w >> 1) * 64;
  float4v acc[4][4];
#pragma unroll
  for (int mt = 0; mt < 4; mt++)
#pragma unroll
    for (int nt = 0; nt < 4; nt++) acc[mt][nt] = zero4();

#pragma unroll 1
  for (int kk = 0; kk < 2; kk++) {
    if (kk) __syncthreads();
#pragma unroll
    for (int i = 0; i < 8; i++) {
      int ci = i * 256 + tid;
      int r = ci >> 4, pos = ci & 15;
      int kc = pos ^ (r & 7);
      ld_lds16(&msa16[(R0 + r) * 256 + kk * 128 + kc * 8], &lsA[ci * 8]);
    }
#pragma unroll
    for (int i = 0; i < 8; i++) {
      int ci = i * 256 + tid;
      int r = ci >> 4, pos = ci & 15;
      int kc = pos ^ (r & 7);
      ld_lds16(&wt[(cb + r) * 256 + kk * 128 + kc * 8], &lsB[ci * 8]);
    }
    WAIT_VM0();
    __syncthreads();
#pragma unroll
    for (int ks = 0; ks < 4; ks++) {
      short8 af[4], bf[4];
#pragma unroll
      for (int mt = 0; mt < 4; mt++) {
        int r = WR + mt * 16 + c;
        int phys = (ks * 4 + q) ^ (r & 7);
        af[mt] = *(const short8*)&lsA[r * 128 + phys * 8];
      }
#pragma unroll
      for (int nt = 0; nt < 4; nt++) {
        int r = WC + nt * 16 + c;
        int phys = (ks * 4 + q) ^ (r & 7);
        bf[nt] = *(const short8*)&lsB[r * 128 + phys * 8];
      }
#pragma unroll
      for (int mt = 0; mt < 4; mt++)
#pragma unroll
        for (int nt = 0; nt < 4; nt++)
          acc[mt][nt] = MFMA16(af[mt], bf[nt], acc[mt][nt]);
    }
  }

  const float* bp = (m == 0) ? bq : (m == 1) ? bk : bv;
  int n = R0 >> 8;
  if (m < 2) {
    // per-head packed: dst[n][h][i][hd]
    short* dst = (short*)(ws + (m == 0 ? Q_OFF : K_OFF));
#pragma unroll
    for (int nt = 0; nt < 4; nt++) {
      int ch = cb + WC + nt * 16 + c;
      float bb = bp[ch];
      int h = ch >> 5, hd = ch & 31;
#pragma unroll
      for (int mt = 0; mt < 4; mt++) {
        int i0 = (R0 & 255) + WR + mt * 16 + q * 4;
#pragma unroll
        for (int r = 0; r < 4; r++)
          dst[((n * HH + h) * 256 + i0 + r) * HDIM + hd] = f2b(acc[mt][nt][r] + bb);
      }
    }
  } else {
    short* vt = (short*)(ws + VT_OFF);
#pragma unroll
    for (int nt = 0; nt < 4; nt++) {
      int ch = cb + WC + nt * 16 + c;
      float bb = bp[ch];
#pragma unroll
      for (int mt = 0; mt < 4; mt++) {
        int j0 = (R0 & 255) + WR + mt * 16 + q * 4;
        short4v s4;
#pragma unroll
        for (int r = 0; r < 4; r++) s4[r] = f2b(acc[mt][nt][r] + bb);
        *(short4v*)&vt[((n * HH + (ch >> 5)) * HDIM + (ch & 31)) * 256 + j0] = s4;
      }
    }
  }
}

// ============================================================================
// K3: attention. 2048 blocks: bx = qq*512 + (n*8+h) so qq-siblings share XCD.
// NEW: K and V staged once per block into LDS via global_load_lds (was: each
// of the 4 waves streamed 32 KB K/V from L2 -> 4x redundant + L2 latency in
// the serial QK->softmax->PV chain). V is source-XOR-swizzled (m173 pattern)
// so its column-slice LDS reads are conflict-free. P overlays the K region
// after a barrier; LDS total 49 KB -> 3 blocks/CU.
// ============================================================================
__global__ __launch_bounds__(256) void k3_attn(char* __restrict__ ws)
{
  // phase 1: lsK = lds[0 .. 8192) shorts (256 x 32, linear)
  //          lsV = lds[16896 .. 25088) shorts (32 x 256, col-swizzled)
  // phase 2: lsP = lds[0 .. 16896) shorts (64 x 264) overlays lsK
  __shared__ __align__(16) short lds[25088];   // 50176 B
  short* lsK = lds;
  short* lsP = lds;
  short* lsV = lds + 16896;
  int bx = blockIdx.x, tid = threadIdx.x;
  int qq = bx >> 9, grp = bx & 511;
  int n = grp >> 3, h = grp & 7;
  int w = tid >> 6, l = tid & 63, q = l >> 4, c = l & 15;
  const short* qh = (const short*)(ws + Q_OFF) + (n * HH + h) * 256 * HDIM;
  const short* kh = (const short*)(ws + K_OFF) + (n * HH + h) * 256 * HDIM;
  const short* vt = (const short*)(ws + VT_OFF) + (n * HH + h) * HDIM * 256;
  const short* pbf = (const short*)(ws + PBF_OFF) + (h * 16 + qq * 4 + w) * 16 * 256;
  short* os = (short*)(ws + O_OFF);
  const float scale = 0.17677669529663687f;   // 1/sqrt(32)
  int i0 = qq * 64 + w * 16;             // this wave's 16 query rows

  // Q fragment (global, 16B/lane) -- issue before staging so it drains with it
  short8 aq = *(const short8*)&qh[(i0 + c) * HDIM + q * 8];

  // stage K linear: 1024 chunks of 16B
#pragma unroll
  for (int i = 0; i < 4; i++) {
    int ci = i * 256 + tid;
    ld_lds16(&kh[ci * 8], &lsK[ci * 8]);
  }
  // stage V with source-XOR swizzle: lds chunk (row,j) <- global chunk (row, j^(row&7))
#pragma unroll
  for (int i = 0; i < 4; i++) {
    int ci = i * 256 + tid;
    int row = ci >> 5, j = ci & 31;
    int sj = j ^ (row & 7);
    ld_lds16(&vt[row * 256 + sj * 8], &lsV[ci * 8]);
  }
  WAIT_VM0();
  __syncthreads();

  float4v s[16];
#pragma unroll
  for (int jt = 0; jt < 16; jt++) {
    short8 bk8 = *(const short8*)&lsK[(jt * 16 + c) * 32 + q * 8];
    s[jt] = MFMA16(aq, bk8, zero4());
  }
  // scale + pair bias from pre-packed fragments (b64 per jt)
#pragma unroll
  for (int jt = 0; jt < 16; jt++) {
    short4v pv = *(const short4v*)&pbf[(jt * 64 + l) * 4];
#pragma unroll
    for (int r = 0; r < 4; r++)
      s[jt][r] = __builtin_fmaf(s[jt][r], scale, b2f(pv[r]));
  }
  float inv[4];
#pragma unroll
  for (int r = 0; r < 4; r++) {
    float m = s[0][r];
#pragma unroll
    for (int jt = 1; jt < 16; jt++) m = fmaxf(m, s[jt][r]);
    m = fmaxf(m, __shfl_xor(m, 1, 64));
    m = fmaxf(m, __shfl_xor(m, 2, 64));
    m = fmaxf(m, __shfl_xor(m, 4, 64));
    m = fmaxf(m, __shfl_xor(m, 8, 64));
    float rs = 0.f;
#pragma unroll
    for (int jt = 0; jt < 16; jt++) {
      float p = __expf(s[jt][r] - m);
      s[jt][r] = p;
      rs += p;
    }
    rs += __shfl_xor(rs, 1, 64);
    rs += __shfl_xor(rs, 2, 64);
    rs += __shfl_xor(rs, 4, 64);
    rs += __shfl_xor(rs, 8, 64);
    inv[r] = 1.f / rs;
  }
  __syncthreads();   // all waves done reading lsK before P overlays it
#pragma unroll
  for (int jt = 0; jt < 16; jt++)
#pragma unroll
    for (int r = 0; r < 4; r++)
      lsP[(w * 16 + q * 4 + r) * 264 + jt * 16 + c] = f2b(s[jt][r]);
  // (no barrier needed: each wave reads only its own 16 P rows)
  float4v o0 = zero4(), o1 = zero4();
#pragma unroll
  for (int kk = 0; kk < 8; kk++) {
    short8 ap = *(const short8*)&lsP[(w * 16 + c) * 264 + kk * 32 + q * 8];
    int sl0 = ((kk * 4 + q) ^ (c & 7)) * 8;
    short8 b0 = *(const short8*)&lsV[c * 256 + sl0];
    short8 b1 = *(const short8*)&lsV[(16 + c) * 256 + sl0];
    o0 = MFMA16(ap, b0, o0);
    o1 = MFMA16(ap, b1, o1);
  }
#pragma unroll
  for (int r = 0; r < 4; r++) {
    os[(n * 256 + i0 + q * 4 + r) * 256 + h * 32 + c]      = f2b(o0[r] * inv[r]);
    os[(n * 256 + i0 + q * 4 + r) * 256 + h * 32 + 16 + c] = f2b(o1[r] * inv[r]);
  }
}

// ============================================================================
// K4: out-proj + bias + residual + LayerNorm. LDS-staged (k2's proven swizzle
// pattern), 32 rows/block: grid 512, 2 blocks/CU.
// ============================================================================
__global__ __launch_bounds__(256) void k4_out(
    const float* __restrict__ msa, const float* __restrict__ bo,
    const float* __restrict__ gamma, const float* __restrict__ beta,
    const char* __restrict__ ws, float* __restrict__ out)
{
  __shared__ __align__(16) short lsA[32 * 128];
  __shared__ __align__(16) short lsB[256 * 128];
  __shared__ float sred[2][32][2];       // [s1|s2][row-in-block][col-half]
  int bx = blockIdx.x, tid = threadIdx.x;
  int w = tid >> 6, l = tid & 63, q = l >> 4, c = l & 15;
  int rg = w >> 1, ch2 = w & 1;          // row-group (0/1), col-half (0/1)
  int R0 = bx * 32;                      // block's 32 rows
  int Rw = R0 + rg * 16;                 // this wave's 16 rows
  int C0 = ch2 * 128;                    // this wave's 128 cols
  const short* osrc = (const short*)(ws + O_OFF);
  const short* wto  = (const short*)(ws + WT_OFF) + 3 * 65536;

  float4v acc[8];
#pragma unroll
  for (int nt = 0; nt < 8; nt++) acc[nt] = zero4();

#pragma unroll 1
  for (int kk = 0; kk < 2; kk++) {
    if (kk) __syncthreads();
#pragma unroll
    for (int i = 0; i < 2; i++) {        // A: 32 rows x 128 k
      int ci = i * 256 + tid;
      int r = ci >> 4, pos = ci & 15;
      int kc = pos ^ (r & 7);
      ld_lds16(&osrc[(R0 + r) * 256 + kk * 128 + kc * 8], &lsA[ci * 8]);
    }
#pragma unroll
    for (int i = 0; i < 16; i++) {       // B: 256 ch x 128 k
      int ci = i * 256 + tid;
      int r = ci >> 4, pos = ci & 15;
      int kc = pos ^ (r & 7);
      ld_lds16(&wto[r * 256 + kk * 128 + kc * 8], &lsB[ci * 8]);
    }
    WAIT_VM0();
    __syncthreads();
#pragma unroll
    for (int ks = 0; ks < 4; ks++) {
      int rA = rg * 16 + c;
      int physA = (ks * 4 + q) ^ (rA & 7);
      short8 af = *(const short8*)&lsA[rA * 128 + physA * 8];
#pragma unroll
      for (int nt = 0; nt < 8; nt++) {
        int rB = C0 + nt * 16 + c;
        int phys = (ks * 4 + q) ^ (rB & 7);
        short8 bf = *(const short8*)&lsB[rB * 128 + phys * 8];
        acc[nt] = MFMA16(af, bf, acc[nt]);
      }
    }
  }

  // bias + residual + stats over this wave's 128 cols
  float s1[4] = {0, 0, 0, 0}, s2[4] = {0, 0, 0, 0};
#pragma unroll
  for (int nt = 0; nt < 8; nt++) {
    float bb = bo[C0 + nt * 16 + c];
#pragma unroll
    for (int r = 0; r < 4; r++) {
      float x = acc[nt][r] + bb + msa[(Rw + q * 4 + r) * 256 + C0 + nt * 16 + c];
      acc[nt][r] = x;
      s1[r] += x;
      s2[r] = __builtin_fmaf(x, x, s2[r]);
    }
  }
  // reduce over the 16 c-lanes (stays within each q-group)
#pragma unroll
  for (int r = 0; r < 4; r++) {
    s1[r] += __shfl_xor(s1[r], 1, 64); s2[r] += __shfl_xor(s2[r], 1, 64);
    s1[r] += __shfl_xor(s1[r], 2, 64); s2[r] += __shfl_xor(s2[r], 2, 64);
    s1[r] += __shfl_xor(s1[r], 4, 64); s2[r] += __shfl_xor(s2[r], 4, 64);
    s1[r] += __shfl_xor(s1[r], 8, 64); s2[r] += __shfl_xor(s2[r], 8, 64);
  }
  if (c == 0) {
#pragma unroll
    for (int r = 0; r < 4; r++) {
      sred[0][rg * 16 + q * 4 + r][ch2] = s1[r];
      sred[1][rg * 16 + q * 4 + r][ch2] = s2[r];
    }
  }
  __syncthreads();
  float mu[4], rsd[4];
#pragma unroll
  for (int r = 0; r < 4; r++) {
    int row = rg * 16 + q * 4 + r;
    float a = sred[0][row][0] + sred[0][row][1];
    float b = sred[1][row][0] + sred[1][row][1];
    float m = a * (1.f / 256.f);
    float v = __builtin_fmaf(-m, m, b * (1.f / 256.f));
    mu[r] = m;
    rsd[r] = rsqrtf(v + 1e-5f);
  }
#pragma unroll
  for (int nt = 0; nt < 8; nt++) {
    float g = gamma[C0 + nt * 16 + c], bt = beta[C0 + nt * 16 + c];
#pragma unroll
    for (int r = 0; r < 4; r++)
      out[(Rw + q * 4 + r) * 256 + C0 + nt * 16 + c] =
          (acc[nt][r] - mu[r]) * rsd[r] * g + bt;
  }
}

extern "C" void kernel_launch(void* const* d_in, const int* in_sizes, int n_in,
                              void* d_out, int out_size, void* d_ws, size_t ws_size,
                              hipStream_t stream)
{
  const float* msa   = (const float*)d_in[0];
  const float* pair  = (const float*)d_in[1];
  const float* Wq    = (const float*)d_in[2];
  const float* bq    = (const float*)d_in[3];
  const float* Wk    = (const float*)d_in[4];
  const float* bk    = (const float*)d_in[5];
  const float* Wv    = (const float*)d_in[6];
  const float* bv    = (const float*)d_in[7];
  const float* Wpb   = (const float*)d_in[8];
  const float* bpb   = (const float*)d_in[9];
  const float* Wo    = (const float*)d_in[10];
  const float* bo    = (const float*)d_in[11];
  const float* gamma = (const float*)d_in[12];
  const float* beta  = (const float*)d_in[13];
  char* ws = (char*)d_ws;
  float* out = (float*)d_out;

  hipLaunchKernelGGL(k1_prep, dim3(1792), dim3(256), 0, stream,
                     msa, pair, Wq, Wk, Wv, Wpb, bpb, Wo, ws);
  hipLaunchKernelGGL(k2_qkv, dim3(896), dim3(256), 0, stream,
                     bq, bk, bv, ws);
  hipLaunchKernelGGL(k3_attn, dim3(2048), dim3(256), 0, stream, ws);
  hipLaunchKernelGGL(k4_out, dim3(512), dim3(256), 0, stream,
                     msa, bo, gamma, beta, ws, out);
}

// Round 5
// 158.035 us; speedup vs baseline: 1.1877x; 1.0612x over previous
//
#include <hip/hip_runtime.h>

// Problem constants
#define NSEQ 64
#define LL   256
#define DD   256
#define HH   8
#define HDIM 32

typedef short short8  __attribute__((ext_vector_type(8)));
typedef short short4v __attribute__((ext_vector_type(4)));
typedef float float4v __attribute__((ext_vector_type(4)));

#define MFMA16(a,b,c) __builtin_amdgcn_mfma_f32_16x16x32_bf16((a),(b),(c),0,0,0)

__device__ __forceinline__ float4v zero4() {
  float4v z;
  z[0] = 0.f; z[1] = 0.f; z[2] = 0.f; z[3] = 0.f;
  return z;
}

__device__ __forceinline__ short f2b(float f) {
  unsigned u = __float_as_uint(f);
  u = (u + 0x7fffu + ((u >> 16) & 1u)) >> 16;   // RNE
  return (short)u;
}

__device__ __forceinline__ float b2f(short s) {
  return __uint_as_float(((unsigned)(unsigned short)s) << 16);
}

// async global->LDS, 16B per lane. LDS dest must be wave-uniform-base + lane*16.
__device__ __forceinline__ void ld_lds16(const void* g, void* l) {
  __builtin_amdgcn_global_load_lds(
      (const __attribute__((address_space(1))) unsigned int*)g,
      (__attribute__((address_space(3))) unsigned int*)l, 16, 0, 0);
}
#define WAIT_VM0() __builtin_amdgcn_s_waitcnt(0x0F70)   // vmcnt(0) only

// ---- workspace layout (bytes); total ~34.5 MB (MSA16 and O share) ----
#define WT_OFF    0                            // 4 x 256x256 bf16 (Wq^T,Wk^T,Wv^T,Wo^T) [ch][k]
#define PB_OFF    (4*65536*2)                  // pb bf16 [h][i][j] (1MB) + fragments (1MB)
#define PBF_OFF   (PB_OFF + 8*65536*2)         // pb bf16 fragments [h][it][jt][lane][4]
#define Q_OFF     (PB_OFF + 8*65536*4)         // per-head q_h[n][h][i][hd] bf16
#define K_OFF     (Q_OFF  + 16384*256*2)       // per-head k_h[n][h][j][hd] bf16
#define VT_OFF    (K_OFF  + 16384*256*2)       // [n][h][hd][j] bf16
#define MSA16_OFF (VT_OFF + 16384*256*2)       // 16384x256 bf16 (dead after k2)
#define O_OFF     MSA16_OFF                    // k3 output overlays MSA16

// ============================================================================
// K1: pb GEMM (256) + weight transpose via LDS (64) + msa->bf16 (512)
//     = 832 blocks.
// pb GEMM: pair panel reg-staged coalesced -> bf16 -> XOR-swizzled LDS
// (was: fragment-pattern cvt8 global reads of the 33.5MB pair stream).
// transpose: 64x64 LDS transpose, coalesced reads + short8 writes
// (was: 2B scalar stores at 512B stride).
// ============================================================================
__global__ __launch_bounds__(256) void k1_prep(
    const float* __restrict__ msa,  const float* __restrict__ pair,
    const float* __restrict__ Wq,   const float* __restrict__ Wk,
    const float* __restrict__ Wv,   const float* __restrict__ Wpb,
    const float* __restrict__ bpb,  const float* __restrict__ Wo,
    char* __restrict__ ws)
{
  __shared__ __align__(16) short shm[4 * 64 * 128];   // 64KB: pair staging / transpose tile
  __shared__ short ldsWt[16 * 136];   // Wpb^T bf16, rows 8..15 zero, ld=136 (pad)
  int bx = blockIdx.x, tid = threadIdx.x;
  if (bx < 256) {
    short* pb16 = (short*)(ws + PB_OFF);
    for (int i = tid; i < 16 * 136; i += 256) ldsWt[i] = 0;
    __syncthreads();
    {
      float4 wv4 = *(const float4*)&Wpb[tid * 4];
      int kk = (tid * 4) >> 3, n0 = (tid * 4) & 7;
      ldsWt[(n0 + 0) * 136 + kk] = f2b(wv4.x);
      ldsWt[(n0 + 1) * 136 + kk] = f2b(wv4.y);
      ldsWt[(n0 + 2) * 136 + kk] = f2b(wv4.z);
      ldsWt[(n0 + 3) * 136 + kk] = f2b(wv4.w);
    }
    __syncthreads();
    int w = tid >> 6, l = tid & 63, q = l >> 4, c = l & 15;
    int base = bx * 256 + w * 64;          // block bx covers pair row i=bx, all j
    // stage pair[base .. base+64)[0..128) -> bf16 LDS, coalesced + swizzled
    short* lsWw = shm + w * 8192;
#pragma unroll
    for (int it = 0; it < 16; it++) {
      int jl = it * 4 + (l >> 4);
      int kc = l & 15;
      const float* src = &pair[(base + jl) * 128 + kc * 8];
      float4 a = *(const float4*)src;
      float4 b = *(const float4*)(src + 4);
      short8 v8;
      v8[0] = f2b(a.x); v8[1] = f2b(a.y); v8[2] = f2b(a.z); v8[3] = f2b(a.w);
      v8[4] = f2b(b.x); v8[5] = f2b(b.y); v8[6] = f2b(b.z); v8[7] = f2b(b.w);
      *(short8*)&lsWw[jl * 128 + ((kc ^ (jl & 7)) * 8)] = v8;
    }
    float bias = bpb[c & 7];
    short8 bf[4];
#pragma unroll
    for (int ks = 0; ks < 4; ks++)
      bf[ks] = *(const short8*)&ldsWt[c * 136 + ks * 32 + q * 8];
    float4v acc[4];
#pragma unroll
    for (int mt = 0; mt < 4; mt++) acc[mt] = zero4();
#pragma unroll
    for (int ks = 0; ks < 4; ks++) {
#pragma unroll
      for (int mt = 0; mt < 4; mt++) {
        int row = mt * 16 + c;
        short8 af = *(const short8*)&lsWw[row * 128 + (((ks * 4 + q) ^ (c & 7)) * 8)];
        acc[mt] = MFMA16(af, bf[ks], acc[mt]);
      }
    }
    if (c < 8) {
#pragma unroll
      for (int mt = 0; mt < 4; mt++) {
        short4v o;
#pragma unroll
        for (int r = 0; r < 4; r++) o[r] = f2b(acc[mt][r] + bias);
        *(short4v*)&pb16[c * 65536 + base + mt * 16 + q * 4] = o;
      }
    }
  } else if (bx < 320) {
    // weight transpose via LDS: 64 blocks, each a 64(k) x 64(n) tile
    int b2 = bx - 256;                  // 0..63
    int mat = b2 >> 4, sub = b2 & 15;
    int k0 = (sub >> 2) * 64, n0 = (sub & 3) * 64;
    const float* W = (mat == 0) ? Wq : (mat == 1) ? Wk : (mat == 2) ? Wv : Wo;
    short* wt = (short*)(ws + WT_OFF) + mat * 65536;
    short* ldsT = shm;                  // 64 x 72
#pragma unroll
    for (int p = 0; p < 4; p++) {
      int kl = p * 16 + (tid >> 4);
      int nl = (tid & 15) * 4;
      float4 v = *(const float4*)&W[(k0 + kl) * 256 + n0 + nl];
      ldsT[(nl + 0) * 72 + kl] = f2b(v.x);
      ldsT[(nl + 1) * 72 + kl] = f2b(v.y);
      ldsT[(nl + 2) * 72 + kl] = f2b(v.z);
      ldsT[(nl + 3) * 72 + kl] = f2b(v.w);
    }
    __syncthreads();
#pragma unroll
    for (int p = 0; p < 2; p++) {
      int id = p * 256 + tid;
      int nl = id >> 3, c8 = id & 7;
      *(short8*)&wt[(n0 + nl) * 256 + k0 + c8 * 8] =
          *(const short8*)&ldsT[nl * 72 + c8 * 8];
    }
  } else {
    // msa -> bf16 row-major
    int b3 = bx - 320;                  // 0..511, 32 rows each
    const float* src = msa + b3 * 8192;
    short* dst = (short*)(ws + MSA16_OFF) + b3 * 8192;
#pragma unroll
    for (int i = 0; i < 8; i++) {
      int idx = i * 1024 + tid * 4;
      float4 v = *(const float4*)&src[idx];
      short4v s;
      s[0] = f2b(v.x); s[1] = f2b(v.y); s[2] = f2b(v.z); s[3] = f2b(v.w);
      *(short4v*)&dst[idx] = s;
    }
  }
}

// ============================================================================
// K2: QKV GEMM (768 blocks) + pb fragment repack (128 blocks) = 896 blocks.
// GEMM: C[16384x768] = msa16 @ [Wq^T;Wk^T;Wv^T], 128x128 tiles, BK=128,
// LDS-staged via global_load_lds + XOR swizzle. NEW epilogue: acc+bias ->
// bf16 LDS tile (ld=136) -> coalesced short8 global stores (was: 64 scalar
// 2B scattered stores per thread for Q/K).
// ============================================================================
__global__ __launch_bounds__(256) void k2_qkv(
    const float* __restrict__ bq, const float* __restrict__ bk,
    const float* __restrict__ bv, char* __restrict__ ws)
{
  __shared__ __align__(16) short ls[2 * 128 * 128];   // lsA | lsB, reused as lsC
  short* lsA = ls;
  short* lsB = ls + 16384;
  int bx = blockIdx.x, tid = threadIdx.x;
  if (bx >= 768) {
    // pb repack: pb16[h][i][j] -> fragments pbf[h][it][jt][lane][reg] (bf16)
    int b = bx - 768;                   // 0..127
    int it16 = b & 15;
    const short* src = (const short*)(ws + PB_OFF) + (b >> 4) * 65536 + it16 * 4096;
    short* pbf = (short*)(ws + PBF_OFF);
    short* lt = lsA;                    // 16 x 264
#pragma unroll
    for (int i2 = 0; i2 < 2; i2++) {
      int idx = i2 * 2048 + tid * 8;
      *(short8*)&lt[(idx >> 8) * 264 + (idx & 255)] = *(const short8*)&src[idx];
    }
    __syncthreads();
#pragma unroll
    for (int i2 = 0; i2 < 4; i2++) {
      int fid = i2 * 256 + tid;
      int jt = fid >> 6, lane = fid & 63;
      int qp = lane >> 4, cp = lane & 15;
      short4v v;
#pragma unroll
      for (int r = 0; r < 4; r++)
        v[r] = lt[(qp * 4 + r) * 264 + jt * 16 + cp];
      *(short4v*)&pbf[((b * 16 + jt) * 64 + lane) * 4] = v;
    }
    return;
  }
  int rt = bx & 127, ct = bx >> 7;       // row-tile, col-tile
  int m = ct >> 1, cb = (ct & 1) * 128;  // matrix, ch base within matrix
  int R0 = rt * 128;
  const short* msa16 = (const short*)(ws + MSA16_OFF);
  const short* wt = (const short*)(ws + WT_OFF) + m * 65536;
  int w = tid >> 6, l = tid & 63, q = l >> 4, c = l & 15;
  int WR = (w & 1) * 64, WC = (w >> 1) * 64;
  float4v acc[4][4];
#pragma unroll
  for (int mt = 0; mt < 4; mt++)
#pragma unroll
    for (int nt = 0; nt < 4; nt++) acc[mt][nt] = zero4();

#pragma unroll 1
  for (int kk = 0; kk < 2; kk++) {
    if (kk) __syncthreads();
#pragma unroll
    for (int i = 0; i < 8; i++) {
      int ci = i * 256 + tid;
      int r = ci >> 4, pos = ci & 15;
      int kc = pos ^ (r & 7);
      ld_lds16(&msa16[(R0 + r) * 256 + kk * 128 + kc * 8], &lsA[ci * 8]);
    }
#pragma unroll
    for (int i = 0; i < 8; i++) {
      int ci = i * 256 + tid;
      int r = ci >> 4, pos = ci & 15;
      int kc = pos ^ (r & 7);
      ld_lds16(&wt[(cb + r) * 256 + kk * 128 + kc * 8], &lsB[ci * 8]);
    }
    WAIT_VM0();
    __syncthreads();
#pragma unroll
    for (int ks = 0; ks < 4; ks++) {
      short8 af[4], bf[4];
#pragma unroll
      for (int mt = 0; mt < 4; mt++) {
        int r = WR + mt * 16 + c;
        int phys = (ks * 4 + q) ^ (r & 7);
        af[mt] = *(const short8*)&lsA[r * 128 + phys * 8];
      }
#pragma unroll
      for (int nt = 0; nt < 4; nt++) {
        int r = WC + nt * 16 + c;
        int phys = (ks * 4 + q) ^ (r & 7);
        bf[nt] = *(const short8*)&lsB[r * 128 + phys * 8];
      }
#pragma unroll
      for (int mt = 0; mt < 4; mt++)
#pragma unroll
        for (int nt = 0; nt < 4; nt++)
          acc[mt][nt] = MFMA16(af[mt], bf[nt], acc[mt][nt]);
    }
  }

  const float* bp = (m == 0) ? bq : (m == 1) ? bk : bv;
  int n = R0 >> 8;
  __syncthreads();                      // all waves done reading lsA/lsB
  short* lsC = ls;                      // 128 x 136 bf16
  if (m < 2) {
    // lsC[i][ch] then coalesced per-head-packed store dst[n][h][i][hd]
#pragma unroll
    for (int nt = 0; nt < 4; nt++) {
      float bb = bp[cb + WC + nt * 16 + c];
#pragma unroll
      for (int mt = 0; mt < 4; mt++)
#pragma unroll
        for (int r = 0; r < 4; r++)
          lsC[(WR + mt * 16 + q * 4 + r) * 136 + WC + nt * 16 + c] =
              f2b(acc[mt][nt][r] + bb);
    }
    __syncthreads();
    short* dst = (short*)(ws + (m == 0 ? Q_OFF : K_OFF)) + n * 65536;
    int ibase = R0 & 255;
#pragma unroll
    for (int p = 0; p < 8; p++) {
      int id = p * 256 + tid;
      int il = id >> 4, ch8 = id & 15;
      int chg = cb + ch8 * 8;
      int hh = chg >> 5, hd0 = chg & 31;
      *(short8*)&dst[(hh * 256 + ibase + il) * 32 + hd0] =
          *(const short8*)&lsC[il * 136 + ch8 * 8];
    }
  } else {
    // lsC[ch][j] then coalesced store vt[n*256+ch][j]
#pragma unroll
    for (int nt = 0; nt < 4; nt++) {
      float bb = bp[cb + WC + nt * 16 + c];
#pragma unroll
      for (int mt = 0; mt < 4; mt++)
#pragma unroll
        for (int r = 0; r < 4; r++)
          lsC[(WC + nt * 16 + c) * 136 + WR + mt * 16 + q * 4 + r] =
              f2b(acc[mt][nt][r] + bb);
    }
    __syncthreads();
    short* vt = (short*)(ws + VT_OFF) + n * 65536;
    int jbase = R0 & 255;
#pragma unroll
    for (int p = 0; p < 8; p++) {
      int id = p * 256 + tid;
      int chl = id >> 4, j8 = id & 15;
      int chg = cb + chl;
      *(short8*)&vt[chg * 256 + jbase + j8 * 8] =
          *(const short8*)&lsC[chl * 136 + j8 * 8];
    }
  }
}

// ============================================================================
// K3: attention. 2048 blocks: bx = qq*512 + (n*8+h) so qq-siblings share XCD.
// K and V staged once per block into LDS via global_load_lds; V source-XOR-
// swizzled; P overlays K region. LDS 49KB -> 3 blocks/CU.
// ============================================================================
__global__ __launch_bounds__(256) void k3_attn(char* __restrict__ ws)
{
  __shared__ __align__(16) short lds[25088];   // 50176 B
  short* lsK = lds;
  short* lsP = lds;
  short* lsV = lds + 16896;
  int bx = blockIdx.x, tid = threadIdx.x;
  int qq = bx >> 9, grp = bx & 511;
  int n = grp >> 3, h = grp & 7;
  int w = tid >> 6, l = tid & 63, q = l >> 4, c = l & 15;
  const short* qh = (const short*)(ws + Q_OFF) + (n * HH + h) * 256 * HDIM;
  const short* kh = (const short*)(ws + K_OFF) + (n * HH + h) * 256 * HDIM;
  const short* vt = (const short*)(ws + VT_OFF) + (n * HH + h) * HDIM * 256;
  const short* pbf = (const short*)(ws + PBF_OFF) + (h * 16 + qq * 4 + w) * 16 * 256;
  short* os = (short*)(ws + O_OFF);
  const float scale = 0.17677669529663687f;   // 1/sqrt(32)
  int i0 = qq * 64 + w * 16;             // this wave's 16 query rows

  short8 aq = *(const short8*)&qh[(i0 + c) * HDIM + q * 8];

#pragma unroll
  for (int i = 0; i < 4; i++) {
    int ci = i * 256 + tid;
    ld_lds16(&kh[ci * 8], &lsK[ci * 8]);
  }
#pragma unroll
  for (int i = 0; i < 4; i++) {
    int ci = i * 256 + tid;
    int row = ci >> 5, j = ci & 31;
    int sj = j ^ (row & 7);
    ld_lds16(&vt[row * 256 + sj * 8], &lsV[ci * 8]);
  }
  WAIT_VM0();
  __syncthreads();

  float4v s[16];
#pragma unroll
  for (int jt = 0; jt < 16; jt++) {
    short8 bk8 = *(const short8*)&lsK[(jt * 16 + c) * 32 + q * 8];
    s[jt] = MFMA16(aq, bk8, zero4());
  }
#pragma unroll
  for (int jt = 0; jt < 16; jt++) {
    short4v pv = *(const short4v*)&pbf[(jt * 64 + l) * 4];
#pragma unroll
    for (int r = 0; r < 4; r++)
      s[jt][r] = __builtin_fmaf(s[jt][r], scale, b2f(pv[r]));
  }
  float inv[4];
#pragma unroll
  for (int r = 0; r < 4; r++) {
    float m = s[0][r];
#pragma unroll
    for (int jt = 1; jt < 16; jt++) m = fmaxf(m, s[jt][r]);
    m = fmaxf(m, __shfl_xor(m, 1, 64));
    m = fmaxf(m, __shfl_xor(m, 2, 64));
    m = fmaxf(m, __shfl_xor(m, 4, 64));
    m = fmaxf(m, __shfl_xor(m, 8, 64));
    float rs = 0.f;
#pragma unroll
    for (int jt = 0; jt < 16; jt++) {
      float p = __expf(s[jt][r] - m);
      s[jt][r] = p;
      rs += p;
    }
    rs += __shfl_xor(rs, 1, 64);
    rs += __shfl_xor(rs, 2, 64);
    rs += __shfl_xor(rs, 4, 64);
    rs += __shfl_xor(rs, 8, 64);
    inv[r] = 1.f / rs;
  }
  __syncthreads();   // all waves done reading lsK before P overlays it
#pragma unroll
  for (int jt = 0; jt < 16; jt++)
#pragma unroll
    for (int r = 0; r < 4; r++)
      lsP[(w * 16 + q * 4 + r) * 264 + jt * 16 + c] = f2b(s[jt][r]);
  float4v o0 = zero4(), o1 = zero4();
#pragma unroll
  for (int kk = 0; kk < 8; kk++) {
    short8 ap = *(const short8*)&lsP[(w * 16 + c) * 264 + kk * 32 + q * 8];
    int sl0 = ((kk * 4 + q) ^ (c & 7)) * 8;
    short8 b0 = *(const short8*)&lsV[c * 256 + sl0];
    short8 b1 = *(const short8*)&lsV[(16 + c) * 256 + sl0];
    o0 = MFMA16(ap, b0, o0);
    o1 = MFMA16(ap, b1, o1);
  }
#pragma unroll
  for (int r = 0; r < 4; r++) {
    os[(n * 256 + i0 + q * 4 + r) * 256 + h * 32 + c]      = f2b(o0[r] * inv[r]);
    os[(n * 256 + i0 + q * 4 + r) * 256 + h * 32 + 16 + c] = f2b(o1[r] * inv[r]);
  }
}

// ============================================================================
// K4: out-proj + bias + residual + LayerNorm. LDS-staged, 32 rows/block:
// grid 512, 2 blocks/CU.
// ============================================================================
__global__ __launch_bounds__(256) void k4_out(
    const float* __restrict__ msa, const float* __restrict__ bo,
    const float* __restrict__ gamma, const float* __restrict__ beta,
    const char* __restrict__ ws, float* __restrict__ out)
{
  __shared__ __align__(16) short lsA[32 * 128];
  __shared__ __align__(16) short lsB[256 * 128];
  __shared__ float sred[2][32][2];       // [s1|s2][row-in-block][col-half]
  int bx = blockIdx.x, tid = threadIdx.x;
  int w = tid >> 6, l = tid & 63, q = l >> 4, c = l & 15;
  int rg = w >> 1, ch2 = w & 1;          // row-group (0/1), col-half (0/1)
  int R0 = bx * 32;                      // block's 32 rows
  int Rw = R0 + rg * 16;                 // this wave's 16 rows
  int C0 = ch2 * 128;                    // this wave's 128 cols
  const short* osrc = (const short*)(ws + O_OFF);
  const short* wto  = (const short*)(ws + WT_OFF) + 3 * 65536;

  float4v acc[8];
#pragma unroll
  for (int nt = 0; nt < 8; nt++) acc[nt] = zero4();

#pragma unroll 1
  for (int kk = 0; kk < 2; kk++) {
    if (kk) __syncthreads();
#pragma unroll
    for (int i = 0; i < 2; i++) {        // A: 32 rows x 128 k
      int ci = i * 256 + tid;
      int r = ci >> 4, pos = ci & 15;
      int kc = pos ^ (r & 7);
      ld_lds16(&osrc[(R0 + r) * 256 + kk * 128 + kc * 8], &lsA[ci * 8]);
    }
#pragma unroll
    for (int i = 0; i < 16; i++) {       // B: 256 ch x 128 k
      int ci = i * 256 + tid;
      int r = ci >> 4, pos = ci & 15;
      int kc = pos ^ (r & 7);
      ld_lds16(&wto[r * 256 + kk * 128 + kc * 8], &lsB[ci * 8]);
    }
    WAIT_VM0();
    __syncthreads();
#pragma unroll
    for (int ks = 0; ks < 4; ks++) {
      int rA = rg * 16 + c;
      int physA = (ks * 4 + q) ^ (rA & 7);
      short8 af = *(const short8*)&lsA[rA * 128 + physA * 8];
#pragma unroll
      for (int nt = 0; nt < 8; nt++) {
        int rB = C0 + nt * 16 + c;
        int phys = (ks * 4 + q) ^ (rB & 7);
        short8 bf = *(const short8*)&lsB[rB * 128 + phys * 8];
        acc[nt] = MFMA16(af, bf, acc[nt]);
      }
    }
  }

  // bias + residual + stats over this wave's 128 cols
  float s1[4] = {0, 0, 0, 0}, s2[4] = {0, 0, 0, 0};
#pragma unroll
  for (int nt = 0; nt < 8; nt++) {
    float bb = bo[C0 + nt * 16 + c];
#pragma unroll
    for (int r = 0; r < 4; r++) {
      float x = acc[nt][r] + bb + msa[(Rw + q * 4 + r) * 256 + C0 + nt * 16 + c];
      acc[nt][r] = x;
      s1[r] += x;
      s2[r] = __builtin_fmaf(x, x, s2[r]);
    }
  }
#pragma unroll
  for (int r = 0; r < 4; r++) {
    s1[r] += __shfl_xor(s1[r], 1, 64); s2[r] += __shfl_xor(s2[r], 1, 64);
    s1[r] += __shfl_xor(s1[r], 2, 64); s2[r] += __shfl_xor(s2[r], 2, 64);
    s1[r] += __shfl_xor(s1[r], 4, 64); s2[r] += __shfl_xor(s2[r], 4, 64);
    s1[r] += __shfl_xor(s1[r], 8, 64); s2[r] += __shfl_xor(s2[r], 8, 64);
  }
  if (c == 0) {
#pragma unroll
    for (int r = 0; r < 4; r++) {
      sred[0][rg * 16 + q * 4 + r][ch2] = s1[r];
      sred[1][rg * 16 + q * 4 + r][ch2] = s2[r];
    }
  }
  __syncthreads();
  float mu[4], rsd[4];
#pragma unroll
  for (int r = 0; r < 4; r++) {
    int row = rg * 16 + q * 4 + r;
    float a = sred[0][row][0] + sred[0][row][1];
    float b = sred[1][row][0] + sred[1][row][1];
    float m = a * (1.f / 256.f);
    float v = __builtin_fmaf(-m, m, b * (1.f / 256.f));
    mu[r] = m;
    rsd[r] = rsqrtf(v + 1e-5f);
  }
#pragma unroll
  for (int nt = 0; nt < 8; nt++) {
    float g = gamma[C0 + nt * 16 + c], bt = beta[C0 + nt * 16 + c];
#pragma unroll
    for (int r = 0; r < 4; r++)
      out[(Rw + q * 4 + r) * 256 + C0 + nt * 16 + c] =
          (acc[nt][r] - mu[r]) * rsd[r] * g + bt;
  }
}

extern "C" void kernel_launch(void* const* d_in, const int* in_sizes, int n_in,
                              void* d_out, int out_size, void* d_ws, size_t ws_size,
                              hipStream_t stream)
{
  const float* msa   = (const float*)d_in[0];
  const float* pair  = (const float*)d_in[1];
  const float* Wq    = (const float*)d_in[2];
  const float* bq    = (const float*)d_in[3];
  const float* Wk    = (const float*)d_in[4];
  const float* bk    = (const float*)d_in[5];
  const float* Wv    = (const float*)d_in[6];
  const float* bv    = (const float*)d_in[7];
  const float* Wpb   = (const float*)d_in[8];
  const float* bpb   = (const float*)d_in[9];
  const float* Wo    = (const float*)d_in[10];
  const float* bo    = (const float*)d_in[11];
  const float* gamma = (const float*)d_in[12];
  const float* beta  = (const float*)d_in[13];
  char* ws = (char*)d_ws;
  float* out = (float*)d_out;

  hipLaunchKernelGGL(k1_prep, dim3(832), dim3(256), 0, stream,
                     msa, pair, Wq, Wk, Wv, Wpb, bpb, Wo, ws);
  hipLaunchKernelGGL(k2_qkv, dim3(896), dim3(256), 0, stream,
                     bq, bk, bv, ws);
  hipLaunchKernelGGL(k3_attn, dim3(2048), dim3(256), 0, stream, ws);
  hipLaunchKernelGGL(k4_out, dim3(512), dim3(256), 0, stream,
                     msa, bo, gamma, beta, ws, out);
}